// Round 6
// baseline (882.780 us; speedup 1.0000x reference)
//
#include <hip/hip_runtime.h>
#include <hip/hip_bf16.h>

#define NN 50000
#define NE 800000
#define DD 64
#define NEG 0.2f

#define RFL(x) __builtin_amdgcn_readfirstlane(x)
__device__ __forceinline__ float rdlane_f(float v, int j) {
    return __int_as_float(__builtin_amdgcn_readlane(__float_as_int(v), j));
}

// ---------------- CSR build ----------------
__global__ void k_hist(const int* __restrict__ dst1, const int* __restrict__ dst2,
                       int* __restrict__ cnt1, int* __restrict__ cnt2) {
    int e = blockIdx.x * blockDim.x + threadIdx.x;
    if (e < NE) {
        atomicAdd(&cnt1[dst1[e]], 1);
        atomicAdd(&cnt2[dst2[e]], 1);
    }
}

__global__ __launch_bounds__(1024) void k_scan(const int* __restrict__ cnt1, int* __restrict__ off1,
                                               const int* __restrict__ cnt2, int* __restrict__ off2) {
    const int* cnt = blockIdx.x ? cnt2 : cnt1;
    int* off = blockIdx.x ? off2 : off1;
    __shared__ int lds[1024];
    const int tid = threadIdx.x;
    const int CH = (NN + 1023) / 1024;  // 49
    const int base = tid * CH;
    int s = 0;
    for (int q = 0; q < CH; ++q) {
        int idx = base + q;
        if (idx < NN) s += cnt[idx];
    }
    lds[tid] = s;
    __syncthreads();
    for (int d = 1; d < 1024; d <<= 1) {
        int v = (tid >= d) ? lds[tid - d] : 0;
        __syncthreads();
        lds[tid] += v;
        __syncthreads();
    }
    int run = tid ? lds[tid - 1] : 0;
    for (int q = 0; q < CH; ++q) {
        int idx = base + q;
        if (idx < NN) { off[idx] = run; run += cnt[idx]; }
    }
    if (tid == 1023) off[NN] = lds[1023];
}

__global__ void k_scatter(const int* __restrict__ src1, const int* __restrict__ dst1,
                          const int* __restrict__ off1, int* __restrict__ fill1, int* __restrict__ csr1,
                          const int* __restrict__ src2, const int* __restrict__ dst2,
                          const int* __restrict__ off2, int* __restrict__ fill2, int* __restrict__ csr2) {
    int e = blockIdx.x * blockDim.x + threadIdx.x;
    if (e < NE) {
        int d1 = dst1[e];
        int p1 = off1[d1] + atomicAdd(&fill1[d1], 1);
        csr1[p1] = src1[e];
        int d2 = dst2[e];
        int p2 = off2[d2] + atomicAdd(&fill2[d2], 1);
        csr2[p2] = src2[e];
    }
}

// ---------------- H1 = x @ W1, alpha1 = H1 @ a1_{src,dst} ----------------
__global__ __launch_bounds__(256) void k_h1(
    const float* __restrict__ x, const float* __restrict__ W1,
    const float* __restrict__ a1s, const float* __restrict__ a1d,
    float* __restrict__ H1, float* __restrict__ al1s, float* __restrict__ al1d) {
    const int lane = threadIdx.x & 63;
    const int i = blockIdx.x * 4 + (threadIdx.x >> 6);
    float wcol[DD];
#pragma unroll
    for (int k = 0; k < DD; ++k) wcol[k] = W1[k * DD + lane];
    const float asv = a1s[lane];
    const float adv = a1d[lane];
    const float xv = x[i * DD + lane];
    float h = 0.f;
#pragma unroll
    for (int k = 0; k < DD; ++k) h = fmaf(__shfl(xv, k), wcol[k], h);
    H1[i * DD + lane] = h;
    float ps = h * asv, pd = h * adv;
#pragma unroll
    for (int o = 32; o; o >>= 1) { ps += __shfl_xor(ps, o); pd += __shfl_xor(pd, o); }
    if (lane == 0) { al1s[i] = ps; al1d[i] = pd; }
}

// ---- layer1, all 9 steps: two-phase edge loop + ELU + @W2 + alpha2 ----
__global__ __launch_bounds__(256) void k_l1(
    const int* __restrict__ off, const int* __restrict__ csrc,
    const float* __restrict__ al1s, const float* __restrict__ al1d,
    const float* __restrict__ H1,
    const float* __restrict__ W2, const float* __restrict__ a2s, const float* __restrict__ a2d,
    uint4* __restrict__ H2a, _Float16* __restrict__ H2b,
    float* __restrict__ al2s8, float* __restrict__ al2s9, float* __restrict__ al2d) {
    const int lane = threadIdx.x & 63;
    const int i = blockIdx.x * 4 + (threadIdx.x >> 6);
    const int p0 = RFL(off[i]);
    const int p1 = RFL(off[i + 1]);
    const float adv = al1d[i];
    float num[9], den[9];
#pragma unroll
    for (int k = 0; k < 9; ++k) { num[k] = 0.f; den[k] = 0.f; }

    for (int base = p0; base < p1; base += 64) {
        int m = p1 - base; if (m > 64) m = 64;
        // phase A: one edge per lane — coalesced index load, parallel gather+exp
        int sv = 0; float rv = 0.f;
        if (lane < m) {
            sv = csrc[base + lane];
            float z = al1s[sv] + adv;
            float c = z > 0.f ? z : NEG * z;      // leaky_relu, step-invariant
            rv = __expf(c * (1.f / 9.f));         // w_k = rv^k
        }
        float w = rv;
#pragma unroll
        for (int k = 0; k < 9; ++k) { den[k] += w; w *= rv; }  // per-lane partials
        // phase B: serial over chunk, broadcast via readlane
        auto body = [&](int j) {
            int sj = __builtin_amdgcn_readlane(sv, j);
            float rj = rdlane_f(rv, j);
            float hv = H1[(size_t)sj * DD + lane];
            float wj = rj;
#pragma unroll
            for (int k = 0; k < 9; ++k) { num[k] = fmaf(wj, hv, num[k]); wj *= rj; }
        };
        int j = 0;
        for (; j + 1 < m; j += 2) { body(j); body(j + 1); }
        if (j < m) body(j);
    }
    // reduce den across lanes
#pragma unroll
    for (int k = 0; k < 9; ++k) {
#pragma unroll
        for (int o = 32; o; o >>= 1) den[k] += __shfl_xor(den[k], o);
    }

    // epilogue: load W2 column only now (keeps loop-phase VGPR pressure low)
    float wcol[DD];
#pragma unroll
    for (int k = 0; k < DD; ++k) wcol[k] = W2[k * DD + lane];
    const float a2sv = a2s[lane];
    const float a2dv = a2d[lane];

    float h2all[9];
#pragma unroll
    for (int k = 0; k < 9; ++k) {
        float t = (float)(k + 1) * (1.f / 9.f);
        float hm = (den[k] > 0.f) ? (t * num[k] / den[k]) : 0.f;
        hm = (hm > 0.f) ? hm : expm1f(hm);        // ELU
        float h2 = 0.f;
#pragma unroll
        for (int j = 0; j < DD; ++j) h2 = fmaf(__shfl(hm, j), wcol[j], h2);
        h2all[k] = h2;
        float ps = h2 * a2sv, pd = h2 * a2dv;
#pragma unroll
        for (int o = 32; o; o >>= 1) { ps += __shfl_xor(ps, o); pd += __shfl_xor(pd, o); }
        if (lane == 0) {
            if (k < 8) al2s8[(size_t)i * 8 + k] = ps;
            else       al2s9[i] = ps;
            al2d[(size_t)i * 9 + k] = pd;
        }
    }
    union { _Float16 h[8]; uint4 u; } pk;
#pragma unroll
    for (int k = 0; k < 8; ++k) pk.h[k] = (_Float16)h2all[k];
    H2a[(size_t)i * DD + lane] = pk.u;
    H2b[(size_t)i * DD + lane] = (_Float16)h2all[8];
}

// ---- layer2, all 9 steps: two-phase edge loop, average into out ----
__global__ __launch_bounds__(256) void k_l2(
    const int* __restrict__ off, const int* __restrict__ csrc,
    const float* __restrict__ al2s8, const float* __restrict__ al2s9,
    const float* __restrict__ al2d,
    const uint4* __restrict__ H2a, const _Float16* __restrict__ H2b,
    float* __restrict__ out) {
    const int lane = threadIdx.x & 63;
    const int i = blockIdx.x * 4 + (threadIdx.x >> 6);
    const int p0 = RFL(off[i]);
    const int p1 = RFL(off[i + 1]);
    float adv[9];
#pragma unroll
    for (int k = 0; k < 9; ++k) adv[k] = al2d[(size_t)i * 9 + k];
    float num[9], den[9];
#pragma unroll
    for (int k = 0; k < 9; ++k) { num[k] = 0.f; den[k] = 0.f; }

    for (int base = p0; base < p1; base += 64) {
        int m = p1 - base; if (m > 64) m = 64;
        // phase A: one edge per lane — parallel alpha gathers + exps
        int sv = 0; float wv[9];
#pragma unroll
        for (int k = 0; k < 9; ++k) wv[k] = 0.f;
        if (lane < m) {
            sv = csrc[base + lane];
            const float4* pa = (const float4*)(al2s8 + (size_t)sv * 8);
            float4 A0 = pa[0], A1 = pa[1];
            float as[9] = {A0.x, A0.y, A0.z, A0.w, A1.x, A1.y, A1.z, A1.w, al2s9[sv]};
#pragma unroll
            for (int k = 0; k < 9; ++k) {
                float z = as[k] + adv[k];
                float lr = z > 0.f ? z : NEG * z;
                wv[k] = __expf(lr);
            }
        }
#pragma unroll
        for (int k = 0; k < 9; ++k) den[k] += wv[k];  // per-lane partials
        // phase B: serial over chunk, readlane-broadcast weights
        auto body = [&](int j) {
            int sj = __builtin_amdgcn_readlane(sv, j);
            union { uint4 v; _Float16 h[8]; } c;
            c.v = H2a[(size_t)sj * DD + lane];
            float h9 = (float)H2b[(size_t)sj * DD + lane];
#pragma unroll
            for (int k = 0; k < 8; ++k)
                num[k] = fmaf(rdlane_f(wv[k], j), (float)c.h[k], num[k]);
            num[8] = fmaf(rdlane_f(wv[8], j), h9, num[8]);
        };
        int j = 0;
        for (; j + 1 < m; j += 2) { body(j); body(j + 1); }
        if (j < m) body(j);
    }
    // reduce den across lanes
#pragma unroll
    for (int k = 0; k < 9; ++k) {
#pragma unroll
        for (int o = 32; o; o >>= 1) den[k] += __shfl_xor(den[k], o);
    }
    float o = 0.f;
#pragma unroll
    for (int k = 0; k < 9; ++k) o += (den[k] > 0.f) ? (num[k] / den[k]) : 0.f;
    out[(size_t)i * DD + lane] = o * (1.f / 9.f);
}

extern "C" void kernel_launch(void* const* d_in, const int* in_sizes, int n_in,
                              void* d_out, int out_size, void* d_ws, size_t ws_size,
                              hipStream_t stream) {
    const float* x   = (const float*)d_in[0];
    const int*   ei1 = (const int*)d_in[1];
    const int*   ei2 = (const int*)d_in[2];
    const float* W1  = (const float*)d_in[3];
    const float* a1s = (const float*)d_in[4];
    const float* a1d = (const float*)d_in[5];
    const float* W2  = (const float*)d_in[6];
    const float* a2s = (const float*)d_in[7];
    const float* a2d = (const float*)d_in[8];
    float* out = (float*)d_out;

    const int* src1 = ei1;
    const int* dst1 = ei1 + NE;
    const int* src2 = ei2;
    const int* dst2 = ei2 + NE;

    // ---- workspace layout (4-byte words), ~81.6 MB total ----
    uint4* H2a   = (uint4*)d_ws;                          // NN*64 uint4 (51.2 MB)
    float* H1    = (float*)d_ws + (size_t)NN * 256;       // NN*DD
    float* al1s  = H1 + (size_t)NN * DD;                  // NN
    float* al1d  = al1s + NN;                             // NN
    float* al2s8 = al1d + NN;                             // NN*8
    float* al2s9 = al2s8 + (size_t)NN * 8;                // NN
    float* al2d  = al2s9 + NN;                            // NN*9
    _Float16* H2b = (_Float16*)(al2d + (size_t)NN * 9);   // NN*DD halves
    int* off1 = (int*)((float*)H2b + (size_t)NN * DD / 2);// NN+1
    int* off2 = off1 + (NN + 1);                          // NN+1
    int* cnt1 = off2 + (NN + 1);                          // NN
    int* cnt2 = cnt1 + NN;                                // NN (contiguous with cnt1)
    int* csr1 = cnt2 + NN;                                // NE
    int* csr2 = csr1 + NE;                                // NE

    const int EB = 256, EG = (NE + EB - 1) / EB;
    const int NB = NN / 4;  // wave per node

    hipMemsetAsync(cnt1, 0, 2 * NN * sizeof(int), stream);
    k_hist<<<EG, EB, 0, stream>>>(dst1, dst2, cnt1, cnt2);
    k_scan<<<2, 1024, 0, stream>>>(cnt1, off1, cnt2, off2);
    hipMemsetAsync(cnt1, 0, 2 * NN * sizeof(int), stream);
    k_scatter<<<EG, EB, 0, stream>>>(src1, dst1, off1, cnt1, csr1,
                                     src2, dst2, off2, cnt2, csr2);
    k_h1<<<NB, 256, 0, stream>>>(x, W1, a1s, a1d, H1, al1s, al1d);

    k_l1<<<NB, 256, 0, stream>>>(off1, csr1, al1s, al1d, H1,
                                 W2, a2s, a2d, H2a, H2b, al2s8, al2s9, al2d);
    k_l2<<<NB, 256, 0, stream>>>(off2, csr2, al2s8, al2s9, al2d, H2a, H2b, out);
}